// Round 9
// baseline (502.849 us; speedup 1.0000x reference)
//
#include <hip/hip_runtime.h>
#include <cstdint>
#include <cstddef>

#define IN_DIM  256
#define H_DIM   256
#define OUT_DIM 128
#define MEDGES  20000

// CSR multisplit geometry — u8-packed counts (4 buckets per u32 word).
// NB=256 merged blocks: one per CU (1024 thr + 120 KB LDS = 1 block/CU), each
// handles BOTH E and V histograms for its chunk in one pass. Safety at
// chunk=3907: per-block bucket count max ~6 (Poisson .195/.039), cumulative
// base <= global bucket total (E ~90, V ~31) — all << 255, no byte carry.
#define NB   256         // count/scatter blocks (1 per CU)
#define NCVT 256         // cvt worker blocks appended to count grid (grid-stride)
#define CT  1024         // threads for count/scatter kernels
#define SCAN_T 256       // threads per scan block; thread owns 1 u32 word = 4 buckets

typedef unsigned short u16;
typedef unsigned int   u32;
typedef short bf16x8 __attribute__((ext_vector_type(8)));
typedef float f32x4  __attribute__((ext_vector_type(4)));

__device__ __forceinline__ float bf2f(u16 u) {
    u32 x = ((u32)u) << 16;
    float f;
    __builtin_memcpy(&f, &x, 4);
    return f;
}
// round-to-nearest-even float -> bf16 (finite inputs)
__device__ __forceinline__ u16 f2bf(float f) {
    u32 x;
    __builtin_memcpy(&x, &f, 4);
    u32 r = x + 0x7fffu + ((x >> 16) & 1u);
    return (u16)(r >> 16);
}

// ======================= fused count (E+V single pass) + cvt =======================
// Blocks [0,NB): zero E+V hist -> one pass over (e_idx,v_idx) with 2 LDS atomics ->
// dump both rows. Blocks [NB,NB+NCVT): grid-stride fp32->bf16 convert of X,W1,W2.
extern __shared__ u32 dyn_lds[];

__global__ __launch_bounds__(1024) void count_cvt(const int* __restrict__ e_idx,
                                                  const int* __restrict__ v_idx,
                                                  u32* __restrict__ counts_e32,
                                                  u32* __restrict__ counts_v32,
                                                  int nnz, int m, int n,
                                                  const float4* __restrict__ X,  ushort4* __restrict__ Xb,  int nX,
                                                  const float4* __restrict__ W1, ushort4* __restrict__ W1b, int nW1,
                                                  const float4* __restrict__ W2, ushort4* __restrict__ W2b, int nW2)
{
    int t = threadIdx.x;
    if ((int)blockIdx.x < NB) {
        int ew = (m + 3) >> 2;
        int vw = (n + 3) >> 2;
        u32* he = dyn_lds;
        u32* hv = dyn_lds + ew;
        int tot = ew + vw;
        for (int w = t; w < tot; w += CT) dyn_lds[w] = 0;
        __syncthreads();
        int r = blockIdx.x;
        int chunk = (nnz + NB - 1) / NB;
        int beg = r * chunk, end = min(nnz, beg + chunk);
        for (int i = beg + t; i < end; i += CT) {
            int e = e_idx[i];
            int v = v_idx[i];
            atomicAdd(&he[e >> 2], 1u << ((e & 3) * 8));
            atomicAdd(&hv[v >> 2], 1u << ((v & 3) * 8));
        }
        __syncthreads();
        u32* rowe = counts_e32 + (size_t)r * ew;
        for (int w = t; w < ew; w += CT) rowe[w] = he[w];
        u32* rowv = counts_v32 + (size_t)r * vw;
        for (int w = t; w < vw; w += CT) rowv[w] = hv[w];
    } else {
        int b = blockIdx.x - NB;
        int ntot = nX + nW1 + nW2;
        for (int i = b * CT + t; i < ntot; i += NCVT * CT) {
            const float4* s; ushort4* d; int k;
            if (i < nX)            { s = X;  d = Xb;  k = i; }
            else if (i < nX + nW1) { s = W1; d = W1b; k = i - nX; }
            else                   { s = W2; d = W2b; k = i - nX - nW1; }
            float4 v = s[k];
            ushort4 o;
            o.x = f2bf(v.x); o.y = f2bf(v.y); o.z = f2bf(v.z); o.w = f2bf(v.w);
            d[k] = o;
        }
    }
}

// Word-packed (u8x4) pipelined column scan over NB rows. Thread owns word w =
// buckets {4w..4w+3}. Rewrites counts in place with per-(block,bucket) exclusive
// bases (bytewise add, no carry by construction); block-scans bucket totals ->
// e_off/v_off (block-local part; addtop finishes it).
__global__ __launch_bounds__(SCAN_T) void scan_block_both(u32* __restrict__ counts_e32,
                                                          u32* __restrict__ counts_v32,
                                                          int* __restrict__ e_off,
                                                          int* __restrict__ v_off,
                                                          int* __restrict__ bsums,
                                                          int m, int n, int nbE)
{
    __shared__ int s[SCAN_T];
    u32* mat; int* out; int* bs; int nwords; int blk; int nn;
    if ((int)blockIdx.x < nbE) { mat = counts_e32; out = e_off; bs = bsums;      nwords = (m + 3) >> 2; blk = blockIdx.x;       nn = m; }
    else                       { mat = counts_v32; out = v_off; bs = bsums + 64; nwords = (n + 3) >> 2; blk = blockIdx.x - nbE; nn = n; }
    int w = blk * SCAN_T + threadIdx.x;
    u32 a = 0;                                   // packed u8x4 running bases
    if (w < nwords) {
        for (int r = 0; r < NB; r += 8) {
            u32 v[8];
#pragma unroll
            for (int k = 0; k < 8; ++k) v[k] = mat[(size_t)(r + k) * nwords + w];
#pragma unroll
            for (int k = 0; k < 8; ++k) {
                mat[(size_t)(r + k) * nwords + w] = a;
                a += v[k];                       // bytewise (no carry by construction)
            }
        }
    }
    int b0 = a & 0xff, b1 = (a >> 8) & 0xff, b2 = (a >> 16) & 0xff, b3 = (int)(a >> 24);
    int x = b0 + b1 + b2 + b3;
    s[threadIdx.x] = x;
    __syncthreads();
    for (int off = 1; off < SCAN_T; off <<= 1) {
        int v = (threadIdx.x >= off) ? s[threadIdx.x - off] : 0;
        __syncthreads();
        s[threadIdx.x] += v;
        __syncthreads();
    }
    if (w < nwords) {
        int ex = s[threadIdx.x] - x;             // exclusive over buckets (block-local)
        int base = 4 * w;
        if (base + 3 < nn) {
            int4 o; o.x = ex; o.y = ex + b0; o.z = ex + b0 + b1; o.w = ex + b0 + b1 + b2;
            *(int4*)&out[base] = o;
        } else {
            if (base     < nn) out[base]     = ex;
            if (base + 1 < nn) out[base + 1] = ex + b0;
            if (base + 2 < nn) out[base + 2] = ex + b0 + b1;
            if (base + 3 < nn) out[base + 3] = ex + b0 + b1 + b2;
        }
    }
    if (threadIdx.x == SCAN_T - 1) bs[blk] = s[SCAN_T - 1];
}

// scan_top merged into scan_add: each block recomputes its bsums prefix with the
// same in-block scan (<=118 scalars), then adds. Tails written by blocks 0 / nbE.
__global__ __launch_bounds__(SCAN_T) void scan_addtop(int* __restrict__ e_off,
                                                      int* __restrict__ v_off,
                                                      const int* __restrict__ bsums,
                                                      int m, int n, int nbE, int nnz)
{
    __shared__ int s[SCAN_T];
    int* out; const int* bs; int nwords; int blk; int nn;
    if ((int)blockIdx.x < nbE) { out = e_off; bs = bsums;      nwords = (m + 3) >> 2; blk = blockIdx.x;       nn = m; }
    else                       { out = v_off; bs = bsums + 64; nwords = (n + 3) >> 2; blk = blockIdx.x - nbE; nn = n; }
    int t = threadIdx.x;
    s[t] = (t < blk) ? bs[t] : 0;                // sum of bsums[0..blk) = block offset
    __syncthreads();
    for (int off = 1; off < SCAN_T; off <<= 1) {
        int v = (t >= off) ? s[t - off] : 0;
        __syncthreads();
        s[t] += v;
        __syncthreads();
    }
    int add = s[SCAN_T - 1];
    if ((int)blockIdx.x == 0   && t == 0) e_off[m] = nnz;
    if ((int)blockIdx.x == nbE && t == 0) v_off[n] = nnz;
    int w = blk * SCAN_T + t;
    if (w < nwords) {
        int base = 4 * w;
        if (base + 3 < nn) {
            int4 o = *(int4*)&out[base];
            o.x += add; o.y += add; o.z += add; o.w += add;
            *(int4*)&out[base] = o;
        } else {
            if (base     < nn) out[base]     += add;
            if (base + 1 < nn) out[base + 1] += add;
            if (base + 2 < nn) out[base + 2] += add;
            if (base + 3 < nn) out[base + 3] += add;
        }
    }
}

// Single-pass scatter: block loads BOTH cursor sets (E+V, 120 KB dynamic LDS),
// reads each pair once, does both placements. Zero global atomics.
__global__ __launch_bounds__(1024) void scatter_all(const int* __restrict__ e_idx,
                                                    const int* __restrict__ v_idx,
                                                    const u32* __restrict__ counts_e32,
                                                    const u32* __restrict__ counts_v32,
                                                    const int* __restrict__ e_off,
                                                    const int* __restrict__ v_off,
                                                    int* __restrict__ e_list,
                                                    int* __restrict__ v_list,
                                                    int nnz, int m, int n)
{
    int t = threadIdx.x;
    int ew = (m + 3) >> 2;
    int vw = (n + 3) >> 2;
    u32* ce = dyn_lds;
    u32* cv = dyn_lds + ew;
    int r = blockIdx.x;
    const u32* rowe = counts_e32 + (size_t)r * ew;
    for (int w = t; w < ew; w += CT) ce[w] = rowe[w];
    const u32* rowv = counts_v32 + (size_t)r * vw;
    for (int w = t; w < vw; w += CT) cv[w] = rowv[w];
    __syncthreads();
    int chunk = (nnz + NB - 1) / NB;
    int beg = r * chunk, end = min(nnz, beg + chunk);
    for (int i = beg + t; i < end; i += CT) {
        int e = e_idx[i];
        int v = v_idx[i];
        int she = (e & 3) * 8;
        u32 olde = atomicAdd(&ce[e >> 2], 1u << she);
        e_list[e_off[e] + (int)((olde >> she) & 0xffu)] = v;
        int shv = (v & 3) * 8;
        u32 oldv = atomicAdd(&cv[v >> 2], 1u << shv);
        v_list[v_off[v] + (int)((oldv >> shv) & 0xffu)] = e;
    }
}

// ======================= segment mean: wave-per-segment =======================
// D = 256: 64 lanes x ushort4 (8 B/lane). 8-deep row pipeline.
__global__ void seg_mean_w4(const ushort4* __restrict__ src, ushort4* __restrict__ dst,
                            const int* __restrict__ off, const int* __restrict__ lst,
                            int nseg, int do_relu)
{
    int wid  = (blockIdx.x * blockDim.x + threadIdx.x) >> 6;
    int lane = threadIdx.x & 63;
    if (wid >= nseg) return;
    int beg = __builtin_amdgcn_readfirstlane(off[wid]);
    int end = __builtin_amdgcn_readfirstlane(off[wid + 1]);
    float ax = 0.f, ay = 0.f, az = 0.f, aw = 0.f;
    int j = beg;
    for (; j + 7 < end; j += 8) {
        ushort4 r[8];
#pragma unroll
        for (int k = 0; k < 8; ++k) r[k] = src[(size_t)lst[j + k] * 64 + lane];
#pragma unroll
        for (int k = 0; k < 8; ++k) {
            ax += bf2f(r[k].x); ay += bf2f(r[k].y);
            az += bf2f(r[k].z); aw += bf2f(r[k].w);
        }
    }
    for (; j + 3 < end; j += 4) {
        ushort4 r[4];
#pragma unroll
        for (int k = 0; k < 4; ++k) r[k] = src[(size_t)lst[j + k] * 64 + lane];
#pragma unroll
        for (int k = 0; k < 4; ++k) {
            ax += bf2f(r[k].x); ay += bf2f(r[k].y);
            az += bf2f(r[k].z); aw += bf2f(r[k].w);
        }
    }
    for (; j < end; ++j) {
        ushort4 a = src[(size_t)lst[j] * 64 + lane];
        ax += bf2f(a.x); ay += bf2f(a.y); az += bf2f(a.z); aw += bf2f(a.w);
    }
    int cnt = end - beg;
    float inv = (cnt > 0) ? 1.f / (float)cnt : 0.f;
    ax *= inv; ay *= inv; az *= inv; aw *= inv;
    if (do_relu) {
        ax = fmaxf(ax, 0.f); ay = fmaxf(ay, 0.f);
        az = fmaxf(az, 0.f); aw = fmaxf(aw, 0.f);
    }
    ushort4 o;
    o.x = f2bf(ax); o.y = f2bf(ay); o.z = f2bf(az); o.w = f2bf(aw);
    dst[(size_t)wid * 64 + lane] = o;
}

// D = 128: ushort2 per lane.
__global__ void seg_mean_w2(const ushort2* __restrict__ src, ushort2* __restrict__ dst,
                            const int* __restrict__ off, const int* __restrict__ lst,
                            int nseg, int do_relu)
{
    int wid  = (blockIdx.x * blockDim.x + threadIdx.x) >> 6;
    int lane = threadIdx.x & 63;
    if (wid >= nseg) return;
    int beg = __builtin_amdgcn_readfirstlane(off[wid]);
    int end = __builtin_amdgcn_readfirstlane(off[wid + 1]);
    float ax = 0.f, ay = 0.f;
    int j = beg;
    for (; j + 7 < end; j += 8) {
        ushort2 r[8];
#pragma unroll
        for (int k = 0; k < 8; ++k) r[k] = src[(size_t)lst[j + k] * 64 + lane];
#pragma unroll
        for (int k = 0; k < 8; ++k) { ax += bf2f(r[k].x); ay += bf2f(r[k].y); }
    }
    for (; j + 3 < end; j += 4) {
        ushort2 r[4];
#pragma unroll
        for (int k = 0; k < 4; ++k) r[k] = src[(size_t)lst[j + k] * 64 + lane];
#pragma unroll
        for (int k = 0; k < 4; ++k) { ax += bf2f(r[k].x); ay += bf2f(r[k].y); }
    }
    for (; j < end; ++j) {
        ushort2 a = src[(size_t)lst[j] * 64 + lane];
        ax += bf2f(a.x); ay += bf2f(a.y);
    }
    int cnt = end - beg;
    float inv = (cnt > 0) ? 1.f / (float)cnt : 0.f;
    ax *= inv; ay *= inv;
    if (do_relu) { ax = fmaxf(ax, 0.f); ay = fmaxf(ay, 0.f); }
    ushort2 o;
    o.x = f2bf(ax); o.y = f2bf(ay);
    dst[(size_t)wid * 64 + lane] = o;
}

// ======================= MFMA bf16 GEMM + bias, bf16 out =======================
#define GSTRIDE 40   // LDS row stride in elements (80 B)
__global__ __launch_bounds__(256) void gemm_mfma_bf16(const u16* __restrict__ A,
                                                      const u16* __restrict__ W,
                                                      const float* __restrict__ bias,
                                                      u16* __restrict__ C,
                                                      int R, int K, int Cc)
{
    __shared__ __align__(16) u16 As[64 * GSTRIDE];   // [row][k] 64x32
    __shared__ __align__(16) u16 Bs[64 * GSTRIDE];   // [n][k]   64x32 (transposed)

    int tid  = threadIdx.x;
    int wave = tid >> 6;
    int lane = tid & 63;
    int quad = lane >> 4;
    int l16  = lane & 15;

    int row0 = blockIdx.y * 64;
    int col0 = blockIdx.x * 64;

    f32x4 acc[4] = {};

    int ar   = tid >> 2;   // 0..63 A row
    int aseg = tid & 3;    // k-offset 8*aseg
    int bk   = tid >> 3;   // 0..31 W k-row
    int bn   = tid & 7;    // n-offset 8*bn

    for (int k0 = 0; k0 < K; k0 += 32) {
        bf16x8 av = {};
        int gr = row0 + ar;
        if (gr < R) av = *(const bf16x8*)&A[(size_t)gr * K + k0 + 8 * aseg];
        *(bf16x8*)&As[ar * GSTRIDE + 8 * aseg] = av;
        bf16x8 wv = *(const bf16x8*)&W[(size_t)(k0 + bk) * Cc + col0 + 8 * bn];
#pragma unroll
        for (int j = 0; j < 8; ++j)
            Bs[(8 * bn + j) * GSTRIDE + bk] = ((const u16*)&wv)[j];
        __syncthreads();

        bf16x8 af = *(const bf16x8*)&As[(16 * wave + l16) * GSTRIDE + 8 * quad];
#pragma unroll
        for (int nt = 0; nt < 4; ++nt) {
            bf16x8 bfv = *(const bf16x8*)&Bs[(16 * nt + l16) * GSTRIDE + 8 * quad];
            acc[nt] = __builtin_amdgcn_mfma_f32_16x16x32_bf16(af, bfv, acc[nt], 0, 0, 0);
        }
        __syncthreads();
    }

#pragma unroll
    for (int nt = 0; nt < 4; ++nt) {
        int col = col0 + 16 * nt + l16;
        float bv = bias[col];
#pragma unroll
        for (int r = 0; r < 4; ++r) {
            int grow = row0 + 16 * wave + 4 * quad + r;
            if (grow < R) C[(size_t)grow * Cc + col] = f2bf(acc[nt][r] + bv);
        }
    }
}

// ======================= link head =======================
__global__ void link_head(const ushort2* __restrict__ h2, const int* __restrict__ link,
                          const float* __restrict__ fc_w, const float* __restrict__ fc_b,
                          float* __restrict__ out, int L)
{
    int gtid = blockIdx.x * blockDim.x + threadIdx.x;
    int wid  = gtid >> 6;
    int lane = threadIdx.x & 63;
    if (wid >= L) return;
    const int Dh = OUT_DIM / 2;   // 64 pairs
    int a = link[2 * wid + 0];
    int b = link[2 * wid + 1];
    ushort2 ra = h2[(size_t)a * Dh + lane];
    ushort2 rb = h2[(size_t)b * Dh + lane];
    float2 w = *(const float2*)&fc_w[2 * lane];
    float acc = 0.5f * ((bf2f(ra.x) + bf2f(rb.x)) * w.x + (bf2f(ra.y) + bf2f(rb.y)) * w.y);
#pragma unroll
    for (int off = 32; off; off >>= 1) acc += __shfl_xor(acc, off, 64);
    if (lane == 0) out[wid] = 1.f / (1.f + expf(-(acc + fc_b[0])));
}

// ======================= launch =======================

static inline size_t align_up(size_t x, size_t a) { return (x + a - 1) & ~(a - 1); }

extern "C" void kernel_launch(void* const* d_in, const int* in_sizes, int n_in,
                              void* d_out, int out_size, void* d_ws, size_t ws_size,
                              hipStream_t stream)
{
    const float* X   = (const float*)d_in[0];
    const float* W1  = (const float*)d_in[1];
    const float* b1  = (const float*)d_in[2];
    const float* W2  = (const float*)d_in[3];
    const float* b2  = (const float*)d_in[4];
    const float* fcw = (const float*)d_in[5];
    const float* fcb = (const float*)d_in[6];
    const int* v_idx = (const int*)d_in[7];
    const int* e_idx = (const int*)d_in[8];
    const int* link  = (const int*)d_in[9];
    float* out = (float*)d_out;

    const int NNZ = in_sizes[7];
    const int N   = in_sizes[0] / IN_DIM;
    const int L   = in_sizes[9] / 2;
    const int M   = MEDGES;

    char* p = (char*)d_ws;
    auto carve = [&](size_t bytes) -> void* {
        void* r = (void*)p;
        p += align_up(bytes, 256);
        return r;
    };
    u16*  Xb    = (u16*)carve((size_t)N * IN_DIM * 2);   // X bf16; reused as h2b (N x 128)
    u16*  h1b   = (u16*)carve((size_t)N * H_DIM * 2);    // h1 bf16
    u16*  Aggb  = (u16*)carve((size_t)M * H_DIM * 2);    // Xe/He bf16 (GEMM A)
    u16*  Yb    = (u16*)carve((size_t)M * H_DIM * 2);    // Y1b / Y2b
    u16*  W1b   = (u16*)carve((size_t)IN_DIM * H_DIM * 2);
    u16*  W2b   = (u16*)carve((size_t)H_DIM * OUT_DIM * 2);
    int*  e_off = (int*)carve((size_t)(M + 1) * 4);
    int*  v_off = (int*)carve((size_t)(N + 1) * 4);
    int*  e_lst = (int*)carve((size_t)NNZ * 4);
    int*  v_lst = (int*)carve((size_t)NNZ * 4);
    int*  bsums = (int*)carve(2048);                     // [0,64) E, [64,64+nbV) V

    // u8x4 counts matrices aliased onto h1b (51.2 MB). Lifetime = count_cvt ..
    // scatter_all, all strictly BEFORE the first h1b write (conv1 e2v seg_mean).
    // counts_e32: 256 x 5000 words = 5.12 MB; counts_v32: 256 x 25000 = 25.6 MB.
    int EW = (M + 3) >> 2;
    int VW = (N + 3) >> 2;
    u32* counts_e32 = (u32*)h1b;
    u32* counts_v32 = counts_e32 + (size_t)NB * EW;

    const int tb = 256;
    const int DYN = (EW + VW) * 4;                       // 120 KB dynamic LDS

    // opt-in for >64 KB dynamic LDS (host-side, graph-capture safe; idempotent)
    (void)hipFuncSetAttribute((const void*)count_cvt,  hipFuncAttributeMaxDynamicSharedMemorySize, DYN);
    (void)hipFuncSetAttribute((const void*)scatter_all, hipFuncAttributeMaxDynamicSharedMemorySize, DYN);

    // fused single-pass E+V count + fp32->bf16 converts (cvt fills idle CUs)
    int nX  = N * IN_DIM / 4;
    int nW1 = IN_DIM * H_DIM / 4;
    int nW2 = H_DIM * OUT_DIM / 4;
    count_cvt<<<NB + NCVT, CT, DYN, stream>>>(e_idx, v_idx, counts_e32, counts_v32,
                                              NNZ, M, N,
                                              (const float4*)X, (ushort4*)Xb, nX,
                                              (const float4*)W1, (ushort4*)W1b, nW1,
                                              (const float4*)W2, (ushort4*)W2b, nW2);

    // u8x4 word-packed pipelined column scan: thread owns 4 buckets (1 u32 word)
    int nbE = (EW + SCAN_T - 1) / SCAN_T;    // 20
    int nbV = (VW + SCAN_T - 1) / SCAN_T;    // 98
    scan_block_both<<<nbE + nbV, SCAN_T, 0, stream>>>(counts_e32, counts_v32,
                                                      e_off, v_off, bsums, M, N, nbE);
    scan_addtop<<<nbE + nbV, SCAN_T, 0, stream>>>(e_off, v_off, bsums, M, N, nbE, NNZ);

    // single-pass scatter (both sides per element), zero global atomics
    scatter_all<<<NB, CT, DYN, stream>>>(e_idx, v_idx, counts_e32, counts_v32,
                                         e_off, v_off, e_lst, v_lst, NNZ, M, N);

    // ---- conv1 ----
    seg_mean_w4<<<((size_t)M * 64 + tb - 1) / tb, tb, 0, stream>>>(
        (const ushort4*)Xb, (ushort4*)Aggb, e_off, e_lst, M, 0);
    gemm_mfma_bf16<<<dim3(H_DIM / 64, (M + 63) / 64), 256, 0, stream>>>(Aggb, W1b, b1, Yb, M, IN_DIM, H_DIM);
    seg_mean_w4<<<((size_t)N * 64 + tb - 1) / tb, tb, 0, stream>>>(
        (const ushort4*)Yb, (ushort4*)h1b, v_off, v_lst, N, 1);

    // ---- conv2 ----
    seg_mean_w4<<<((size_t)M * 64 + tb - 1) / tb, tb, 0, stream>>>(
        (const ushort4*)h1b, (ushort4*)Aggb, e_off, e_lst, M, 0);
    gemm_mfma_bf16<<<dim3(OUT_DIM / 64, (M + 63) / 64), 256, 0, stream>>>(Aggb, W2b, b2, Yb, M, H_DIM, OUT_DIM);
    seg_mean_w2<<<((size_t)N * 64 + tb - 1) / tb, tb, 0, stream>>>(
        (const ushort2*)Yb, (ushort2*)Xb, v_off, v_lst, N, 1);

    // ---- link head ----
    link_head<<<((size_t)L * 64 + tb - 1) / tb, tb, 0, stream>>>(
        (const ushort2*)Xb, link, fcw, fcb, out, L);
}

// Round 10
// 491.610 us; speedup vs baseline: 1.0229x; 1.0229x over previous
//
#include <hip/hip_runtime.h>
#include <cstdint>
#include <cstddef>

#define IN_DIM  256
#define H_DIM   256
#define OUT_DIM 128
#define MEDGES  20000

// CSR multisplit geometry — u8-packed counts (4 buckets per u32 word).
// NB=128 merged blocks (measured best; NB=256 was neutral-to-worse, R9): each
// handles BOTH E and V histograms for its chunk in one pass (120 KB dynamic LDS).
// Safety: per-block bucket count max ~6, cumulative base <= global bucket total
// (E ~90, V ~31) — all << 255, no byte carry.
#define NB   128         // count/scatter blocks
#define NCVT 256         // cvt worker blocks appended to count grid (grid-stride)
#define CT  1024         // threads for count/scatter kernels
#define SCAN_T 256       // threads per scan block; thread owns 1 u32 word = 4 buckets

typedef unsigned short u16;
typedef unsigned int   u32;
typedef short bf16x8 __attribute__((ext_vector_type(8)));
typedef float f32x4  __attribute__((ext_vector_type(4)));

__device__ __forceinline__ float bf2f(u16 u) {
    u32 x = ((u32)u) << 16;
    float f;
    __builtin_memcpy(&f, &x, 4);
    return f;
}
// round-to-nearest-even float -> bf16 (finite inputs)
__device__ __forceinline__ u16 f2bf(float f) {
    u32 x;
    __builtin_memcpy(&x, &f, 4);
    u32 r = x + 0x7fffu + ((x >> 16) & 1u);
    return (u16)(r >> 16);
}

// ======================= fused count (E+V single pass) + cvt =======================
// Blocks [0,NB): zero E+V hist -> one pass over (e_idx,v_idx) with 2 LDS atomics ->
// dump both rows. Blocks [NB,NB+NCVT): grid-stride fp32->bf16 convert of X,W1,W2.
extern __shared__ u32 dyn_lds[];

__global__ __launch_bounds__(1024) void count_cvt(const int* __restrict__ e_idx,
                                                  const int* __restrict__ v_idx,
                                                  u32* __restrict__ counts_e32,
                                                  u32* __restrict__ counts_v32,
                                                  int nnz, int m, int n,
                                                  const float4* __restrict__ X,  ushort4* __restrict__ Xb,  int nX,
                                                  const float4* __restrict__ W1, ushort4* __restrict__ W1b, int nW1,
                                                  const float4* __restrict__ W2, ushort4* __restrict__ W2b, int nW2)
{
    int t = threadIdx.x;
    if ((int)blockIdx.x < NB) {
        int ew = (m + 3) >> 2;
        int vw = (n + 3) >> 2;
        u32* he = dyn_lds;
        u32* hv = dyn_lds + ew;
        int tot = ew + vw;
        for (int w = t; w < tot; w += CT) dyn_lds[w] = 0;
        __syncthreads();
        int r = blockIdx.x;
        int chunk = (nnz + NB - 1) / NB;
        int beg = r * chunk, end = min(nnz, beg + chunk);
        for (int i = beg + t; i < end; i += CT) {
            int e = e_idx[i];
            int v = v_idx[i];
            atomicAdd(&he[e >> 2], 1u << ((e & 3) * 8));
            atomicAdd(&hv[v >> 2], 1u << ((v & 3) * 8));
        }
        __syncthreads();
        u32* rowe = counts_e32 + (size_t)r * ew;
        for (int w = t; w < ew; w += CT) rowe[w] = he[w];
        u32* rowv = counts_v32 + (size_t)r * vw;
        for (int w = t; w < vw; w += CT) rowv[w] = hv[w];
    } else {
        int b = blockIdx.x - NB;
        int ntot = nX + nW1 + nW2;
        for (int i = b * CT + t; i < ntot; i += NCVT * CT) {
            const float4* s; ushort4* d; int k;
            if (i < nX)            { s = X;  d = Xb;  k = i; }
            else if (i < nX + nW1) { s = W1; d = W1b; k = i - nX; }
            else                   { s = W2; d = W2b; k = i - nX - nW1; }
            float4 v = s[k];
            ushort4 o;
            o.x = f2bf(v.x); o.y = f2bf(v.y); o.z = f2bf(v.z); o.w = f2bf(v.w);
            d[k] = o;
        }
    }
}

// Word-packed (u8x4) pipelined column scan over NB rows.
__global__ __launch_bounds__(SCAN_T) void scan_block_both(u32* __restrict__ counts_e32,
                                                          u32* __restrict__ counts_v32,
                                                          int* __restrict__ e_off,
                                                          int* __restrict__ v_off,
                                                          int* __restrict__ bsums,
                                                          int m, int n, int nbE)
{
    __shared__ int s[SCAN_T];
    u32* mat; int* out; int* bs; int nwords; int blk; int nn;
    if ((int)blockIdx.x < nbE) { mat = counts_e32; out = e_off; bs = bsums;      nwords = (m + 3) >> 2; blk = blockIdx.x;       nn = m; }
    else                       { mat = counts_v32; out = v_off; bs = bsums + 64; nwords = (n + 3) >> 2; blk = blockIdx.x - nbE; nn = n; }
    int w = blk * SCAN_T + threadIdx.x;
    u32 a = 0;                                   // packed u8x4 running bases
    if (w < nwords) {
        for (int r = 0; r < NB; r += 8) {
            u32 v[8];
#pragma unroll
            for (int k = 0; k < 8; ++k) v[k] = mat[(size_t)(r + k) * nwords + w];
#pragma unroll
            for (int k = 0; k < 8; ++k) {
                mat[(size_t)(r + k) * nwords + w] = a;
                a += v[k];                       // bytewise (no carry by construction)
            }
        }
    }
    int b0 = a & 0xff, b1 = (a >> 8) & 0xff, b2 = (a >> 16) & 0xff, b3 = (int)(a >> 24);
    int x = b0 + b1 + b2 + b3;
    s[threadIdx.x] = x;
    __syncthreads();
    for (int off = 1; off < SCAN_T; off <<= 1) {
        int v = (threadIdx.x >= off) ? s[threadIdx.x - off] : 0;
        __syncthreads();
        s[threadIdx.x] += v;
        __syncthreads();
    }
    if (w < nwords) {
        int ex = s[threadIdx.x] - x;             // exclusive over buckets (block-local)
        int base = 4 * w;
        if (base + 3 < nn) {
            int4 o; o.x = ex; o.y = ex + b0; o.z = ex + b0 + b1; o.w = ex + b0 + b1 + b2;
            *(int4*)&out[base] = o;
        } else {
            if (base     < nn) out[base]     = ex;
            if (base + 1 < nn) out[base + 1] = ex + b0;
            if (base + 2 < nn) out[base + 2] = ex + b0 + b1;
            if (base + 3 < nn) out[base + 3] = ex + b0 + b1 + b2;
        }
    }
    if (threadIdx.x == SCAN_T - 1) bs[blk] = s[SCAN_T - 1];
}

// scan_top merged into scan_add: each block recomputes its bsums prefix in-block.
__global__ __launch_bounds__(SCAN_T) void scan_addtop(int* __restrict__ e_off,
                                                      int* __restrict__ v_off,
                                                      const int* __restrict__ bsums,
                                                      int m, int n, int nbE, int nnz)
{
    __shared__ int s[SCAN_T];
    int* out; const int* bs; int nwords; int blk; int nn;
    if ((int)blockIdx.x < nbE) { out = e_off; bs = bsums;      nwords = (m + 3) >> 2; blk = blockIdx.x;       nn = m; }
    else                       { out = v_off; bs = bsums + 64; nwords = (n + 3) >> 2; blk = blockIdx.x - nbE; nn = n; }
    int t = threadIdx.x;
    s[t] = (t < blk) ? bs[t] : 0;
    __syncthreads();
    for (int off = 1; off < SCAN_T; off <<= 1) {
        int v = (t >= off) ? s[t - off] : 0;
        __syncthreads();
        s[t] += v;
        __syncthreads();
    }
    int add = s[SCAN_T - 1];
    if ((int)blockIdx.x == 0   && t == 0) e_off[m] = nnz;
    if ((int)blockIdx.x == nbE && t == 0) v_off[n] = nnz;
    int w = blk * SCAN_T + t;
    if (w < nwords) {
        int base = 4 * w;
        if (base + 3 < nn) {
            int4 o = *(int4*)&out[base];
            o.x += add; o.y += add; o.z += add; o.w += add;
            *(int4*)&out[base] = o;
        } else {
            if (base     < nn) out[base]     += add;
            if (base + 1 < nn) out[base + 1] += add;
            if (base + 2 < nn) out[base + 2] += add;
            if (base + 3 < nn) out[base + 3] += add;
        }
    }
}

// Single-pass scatter: both cursor sets in 120 KB dynamic LDS, zero global atomics.
__global__ __launch_bounds__(1024) void scatter_all(const int* __restrict__ e_idx,
                                                    const int* __restrict__ v_idx,
                                                    const u32* __restrict__ counts_e32,
                                                    const u32* __restrict__ counts_v32,
                                                    const int* __restrict__ e_off,
                                                    const int* __restrict__ v_off,
                                                    int* __restrict__ e_list,
                                                    int* __restrict__ v_list,
                                                    int nnz, int m, int n)
{
    int t = threadIdx.x;
    int ew = (m + 3) >> 2;
    int vw = (n + 3) >> 2;
    u32* ce = dyn_lds;
    u32* cv = dyn_lds + ew;
    int r = blockIdx.x;
    const u32* rowe = counts_e32 + (size_t)r * ew;
    for (int w = t; w < ew; w += CT) ce[w] = rowe[w];
    const u32* rowv = counts_v32 + (size_t)r * vw;
    for (int w = t; w < vw; w += CT) cv[w] = rowv[w];
    __syncthreads();
    int chunk = (nnz + NB - 1) / NB;
    int beg = r * chunk, end = min(nnz, beg + chunk);
    for (int i = beg + t; i < end; i += CT) {
        int e = e_idx[i];
        int v = v_idx[i];
        int she = (e & 3) * 8;
        u32 olde = atomicAdd(&ce[e >> 2], 1u << she);
        e_list[e_off[e] + (int)((olde >> she) & 0xffu)] = v;
        int shv = (v & 3) * 8;
        u32 oldv = atomicAdd(&cv[v >> 2], 1u << shv);
        v_list[v_off[v] + (int)((oldv >> shv) & 0xffu)] = e;
    }
}

// ======================= segment mean: wave-per-segment =======================
// D = 256: 64 lanes x ushort4 (8 B/lane). 8-deep row pipeline.
__global__ void seg_mean_w4(const ushort4* __restrict__ src, ushort4* __restrict__ dst,
                            const int* __restrict__ off, const int* __restrict__ lst,
                            int nseg, int do_relu)
{
    int wid  = (blockIdx.x * blockDim.x + threadIdx.x) >> 6;
    int lane = threadIdx.x & 63;
    if (wid >= nseg) return;
    int beg = __builtin_amdgcn_readfirstlane(off[wid]);
    int end = __builtin_amdgcn_readfirstlane(off[wid + 1]);
    float ax = 0.f, ay = 0.f, az = 0.f, aw = 0.f;
    int j = beg;
    for (; j + 7 < end; j += 8) {
        ushort4 r[8];
#pragma unroll
        for (int k = 0; k < 8; ++k) r[k] = src[(size_t)lst[j + k] * 64 + lane];
#pragma unroll
        for (int k = 0; k < 8; ++k) {
            ax += bf2f(r[k].x); ay += bf2f(r[k].y);
            az += bf2f(r[k].z); aw += bf2f(r[k].w);
        }
    }
    for (; j + 3 < end; j += 4) {
        ushort4 r[4];
#pragma unroll
        for (int k = 0; k < 4; ++k) r[k] = src[(size_t)lst[j + k] * 64 + lane];
#pragma unroll
        for (int k = 0; k < 4; ++k) {
            ax += bf2f(r[k].x); ay += bf2f(r[k].y);
            az += bf2f(r[k].z); aw += bf2f(r[k].w);
        }
    }
    for (; j < end; ++j) {
        ushort4 a = src[(size_t)lst[j] * 64 + lane];
        ax += bf2f(a.x); ay += bf2f(a.y); az += bf2f(a.z); aw += bf2f(a.w);
    }
    int cnt = end - beg;
    float inv = (cnt > 0) ? 1.f / (float)cnt : 0.f;
    ax *= inv; ay *= inv; az *= inv; aw *= inv;
    if (do_relu) {
        ax = fmaxf(ax, 0.f); ay = fmaxf(ay, 0.f);
        az = fmaxf(az, 0.f); aw = fmaxf(aw, 0.f);
    }
    ushort4 o;
    o.x = f2bf(ax); o.y = f2bf(ay); o.z = f2bf(az); o.w = f2bf(aw);
    dst[(size_t)wid * 64 + lane] = o;
}

// ======================= fused e2v mean + ReLU + fc dot (conv2 head fold) =======================
// D = 128: ushort2 per lane. The head is linear in h2: out = sigmoid(0.5*(z[a]+z[b])+b)
// with z[v] = relu(mean_row)·fc_w. Compute z directly — h2 (25.6 MB) never materialized.
__global__ void seg_mean_link(const ushort2* __restrict__ src, float* __restrict__ z,
                              const int* __restrict__ off, const int* __restrict__ lst,
                              const float* __restrict__ fc_w, int nseg)
{
    int wid  = (blockIdx.x * blockDim.x + threadIdx.x) >> 6;
    int lane = threadIdx.x & 63;
    if (wid >= nseg) return;
    int beg = __builtin_amdgcn_readfirstlane(off[wid]);
    int end = __builtin_amdgcn_readfirstlane(off[wid + 1]);
    float ax = 0.f, ay = 0.f;
    int j = beg;
    for (; j + 7 < end; j += 8) {
        ushort2 r[8];
#pragma unroll
        for (int k = 0; k < 8; ++k) r[k] = src[(size_t)lst[j + k] * 64 + lane];
#pragma unroll
        for (int k = 0; k < 8; ++k) { ax += bf2f(r[k].x); ay += bf2f(r[k].y); }
    }
    for (; j + 3 < end; j += 4) {
        ushort2 r[4];
#pragma unroll
        for (int k = 0; k < 4; ++k) r[k] = src[(size_t)lst[j + k] * 64 + lane];
#pragma unroll
        for (int k = 0; k < 4; ++k) { ax += bf2f(r[k].x); ay += bf2f(r[k].y); }
    }
    for (; j < end; ++j) {
        ushort2 a = src[(size_t)lst[j] * 64 + lane];
        ax += bf2f(a.x); ay += bf2f(a.y);
    }
    int cnt = end - beg;
    float inv = (cnt > 0) ? 1.f / (float)cnt : 0.f;
    ax = fmaxf(ax * inv, 0.f);
    ay = fmaxf(ay * inv, 0.f);
    float2 w = *(const float2*)&fc_w[2 * lane];
    float p = ax * w.x + ay * w.y;
#pragma unroll
    for (int off2 = 32; off2; off2 >>= 1) p += __shfl_xor(p, off2, 64);
    if (lane == 0) z[wid] = p;
}

// ======================= MFMA bf16 GEMM + bias, bf16 out =======================
#define GSTRIDE 40   // LDS row stride in elements (80 B)
__global__ __launch_bounds__(256) void gemm_mfma_bf16(const u16* __restrict__ A,
                                                      const u16* __restrict__ W,
                                                      const float* __restrict__ bias,
                                                      u16* __restrict__ C,
                                                      int R, int K, int Cc)
{
    __shared__ __align__(16) u16 As[64 * GSTRIDE];   // [row][k] 64x32
    __shared__ __align__(16) u16 Bs[64 * GSTRIDE];   // [n][k]   64x32 (transposed)

    int tid  = threadIdx.x;
    int wave = tid >> 6;
    int lane = tid & 63;
    int quad = lane >> 4;
    int l16  = lane & 15;

    int row0 = blockIdx.y * 64;
    int col0 = blockIdx.x * 64;

    f32x4 acc[4] = {};

    int ar   = tid >> 2;   // 0..63 A row
    int aseg = tid & 3;    // k-offset 8*aseg
    int bk   = tid >> 3;   // 0..31 W k-row
    int bn   = tid & 7;    // n-offset 8*bn

    for (int k0 = 0; k0 < K; k0 += 32) {
        bf16x8 av = {};
        int gr = row0 + ar;
        if (gr < R) av = *(const bf16x8*)&A[(size_t)gr * K + k0 + 8 * aseg];
        *(bf16x8*)&As[ar * GSTRIDE + 8 * aseg] = av;
        bf16x8 wv = *(const bf16x8*)&W[(size_t)(k0 + bk) * Cc + col0 + 8 * bn];
#pragma unroll
        for (int j = 0; j < 8; ++j)
            Bs[(8 * bn + j) * GSTRIDE + bk] = ((const u16*)&wv)[j];
        __syncthreads();

        bf16x8 af = *(const bf16x8*)&As[(16 * wave + l16) * GSTRIDE + 8 * quad];
#pragma unroll
        for (int nt = 0; nt < 4; ++nt) {
            bf16x8 bfv = *(const bf16x8*)&Bs[(16 * nt + l16) * GSTRIDE + 8 * quad];
            acc[nt] = __builtin_amdgcn_mfma_f32_16x16x32_bf16(af, bfv, acc[nt], 0, 0, 0);
        }
        __syncthreads();
    }

#pragma unroll
    for (int nt = 0; nt < 4; ++nt) {
        int col = col0 + 16 * nt + l16;
        float bv = bias[col];
#pragma unroll
        for (int r = 0; r < 4; ++r) {
            int grow = row0 + 16 * wave + 4 * quad + r;
            if (grow < R) C[(size_t)grow * Cc + col] = f2bf(acc[nt][r] + bv);
        }
    }
}

// ======================= scalar link head (z-based) =======================
__global__ void link_head_z(const float* __restrict__ z, const int* __restrict__ link,
                            const float* __restrict__ fc_b, float* __restrict__ out, int L)
{
    int i = blockIdx.x * blockDim.x + threadIdx.x;
    if (i >= L) return;
    int a = link[2 * i + 0];
    int b = link[2 * i + 1];
    float s = 0.5f * (z[a] + z[b]) + fc_b[0];
    out[i] = 1.f / (1.f + expf(-s));
}

// ======================= launch =======================

static inline size_t align_up(size_t x, size_t a) { return (x + a - 1) & ~(a - 1); }

extern "C" void kernel_launch(void* const* d_in, const int* in_sizes, int n_in,
                              void* d_out, int out_size, void* d_ws, size_t ws_size,
                              hipStream_t stream)
{
    const float* X   = (const float*)d_in[0];
    const float* W1  = (const float*)d_in[1];
    const float* b1  = (const float*)d_in[2];
    const float* W2  = (const float*)d_in[3];
    const float* b2  = (const float*)d_in[4];
    const float* fcw = (const float*)d_in[5];
    const float* fcb = (const float*)d_in[6];
    const int* v_idx = (const int*)d_in[7];
    const int* e_idx = (const int*)d_in[8];
    const int* link  = (const int*)d_in[9];
    float* out = (float*)d_out;

    const int NNZ = in_sizes[7];
    const int N   = in_sizes[0] / IN_DIM;
    const int L   = in_sizes[9] / 2;
    const int M   = MEDGES;

    char* p = (char*)d_ws;
    auto carve = [&](size_t bytes) -> void* {
        void* r = (void*)p;
        p += align_up(bytes, 256);
        return r;
    };
    u16*  Xb    = (u16*)carve((size_t)N * IN_DIM * 2);   // X bf16
    u16*  h1b   = (u16*)carve((size_t)N * H_DIM * 2);    // h1 bf16
    u16*  Aggb  = (u16*)carve((size_t)M * H_DIM * 2);    // Xe/He bf16 (GEMM A)
    u16*  Yb    = (u16*)carve((size_t)M * H_DIM * 2);    // Y1b / Y2b
    u16*  W1b   = (u16*)carve((size_t)IN_DIM * H_DIM * 2);
    u16*  W2b   = (u16*)carve((size_t)H_DIM * OUT_DIM * 2);
    int*  e_off = (int*)carve((size_t)(M + 1) * 4);
    int*  v_off = (int*)carve((size_t)(N + 1) * 4);
    int*  e_lst = (int*)carve((size_t)NNZ * 4);
    int*  v_lst = (int*)carve((size_t)NNZ * 4);
    int*  bsums = (int*)carve(2048);                     // [0,64) E, [64,64+nbV) V
    float* zv   = (float*)carve((size_t)N * 4);          // per-vertex head scalar

    // u8x4 counts matrices aliased onto h1b (51.2 MB). Lifetime = count_cvt ..
    // scatter_all, all strictly BEFORE the first h1b write (conv1 e2v seg_mean).
    // counts_e32: 128 x 5000 words = 2.56 MB; counts_v32: 128 x 25000 = 12.8 MB.
    int EW = (M + 3) >> 2;
    int VW = (N + 3) >> 2;
    u32* counts_e32 = (u32*)h1b;
    u32* counts_v32 = counts_e32 + (size_t)NB * EW;

    const int tb = 256;
    const int DYN = (EW + VW) * 4;                       // 120 KB dynamic LDS

    // opt-in for >64 KB dynamic LDS (host-side, graph-capture safe; idempotent)
    (void)hipFuncSetAttribute((const void*)count_cvt,  hipFuncAttributeMaxDynamicSharedMemorySize, DYN);
    (void)hipFuncSetAttribute((const void*)scatter_all, hipFuncAttributeMaxDynamicSharedMemorySize, DYN);

    // fused single-pass E+V count + fp32->bf16 converts (cvt fills idle CUs)
    int nX  = N * IN_DIM / 4;
    int nW1 = IN_DIM * H_DIM / 4;
    int nW2 = H_DIM * OUT_DIM / 4;
    count_cvt<<<NB + NCVT, CT, DYN, stream>>>(e_idx, v_idx, counts_e32, counts_v32,
                                              NNZ, M, N,
                                              (const float4*)X, (ushort4*)Xb, nX,
                                              (const float4*)W1, (ushort4*)W1b, nW1,
                                              (const float4*)W2, (ushort4*)W2b, nW2);

    // u8x4 word-packed pipelined column scan: thread owns 4 buckets (1 u32 word)
    int nbE = (EW + SCAN_T - 1) / SCAN_T;    // 20
    int nbV = (VW + SCAN_T - 1) / SCAN_T;    // 98
    scan_block_both<<<nbE + nbV, SCAN_T, 0, stream>>>(counts_e32, counts_v32,
                                                      e_off, v_off, bsums, M, N, nbE);
    scan_addtop<<<nbE + nbV, SCAN_T, 0, stream>>>(e_off, v_off, bsums, M, N, nbE, NNZ);

    // single-pass scatter (both sides per element), zero global atomics
    scatter_all<<<NB, CT, DYN, stream>>>(e_idx, v_idx, counts_e32, counts_v32,
                                         e_off, v_off, e_lst, v_lst, NNZ, M, N);

    // ---- conv1 ----
    seg_mean_w4<<<((size_t)M * 64 + tb - 1) / tb, tb, 0, stream>>>(
        (const ushort4*)Xb, (ushort4*)Aggb, e_off, e_lst, M, 0);
    gemm_mfma_bf16<<<dim3(H_DIM / 64, (M + 63) / 64), 256, 0, stream>>>(Aggb, W1b, b1, Yb, M, IN_DIM, H_DIM);
    seg_mean_w4<<<((size_t)N * 64 + tb - 1) / tb, tb, 0, stream>>>(
        (const ushort4*)Yb, (ushort4*)h1b, v_off, v_lst, N, 1);

    // ---- conv2 ----
    seg_mean_w4<<<((size_t)M * 64 + tb - 1) / tb, tb, 0, stream>>>(
        (const ushort4*)h1b, (ushort4*)Aggb, e_off, e_lst, M, 0);
    gemm_mfma_bf16<<<dim3(OUT_DIM / 64, (M + 63) / 64), 256, 0, stream>>>(Aggb, W2b, b2, Yb, M, H_DIM, OUT_DIM);
    // fused e2v mean + relu + fc dot: h2 never materialized (saves 25.6 MB write
    // + link_head's 100K random 128 B row-gathers)
    seg_mean_link<<<((size_t)N * 64 + tb - 1) / tb, tb, 0, stream>>>(
        (const ushort2*)Yb, zv, v_off, v_lst, fcw, N);

    // ---- link head (scalar) ----
    link_head_z<<<(L + tb - 1) / tb, tb, 0, stream>>>(zv, link, fcb, out, L);
}

// Round 11
// 483.722 us; speedup vs baseline: 1.0395x; 1.0163x over previous
//
#include <hip/hip_runtime.h>
#include <cstdint>
#include <cstddef>

#define IN_DIM  256
#define H_DIM   256
#define OUT_DIM 128
#define MEDGES  20000

// CSR multisplit geometry — u8-packed counts (4 buckets per u32 word).
// NB=128 merged blocks (measured best; NB=256 neutral-to-worse, R9).
#define NB   128         // count/scatter blocks
#define NCVT 256         // cvt worker blocks appended to count grid (grid-stride)
#define CT  1024         // threads for count/scatter kernels
#define SCAN_T 256       // threads per scan block; thread owns 1 u32 word = 4 buckets

typedef unsigned short u16;
typedef unsigned int   u32;
typedef short bf16x8 __attribute__((ext_vector_type(8)));
typedef float f32x4  __attribute__((ext_vector_type(4)));

__device__ __forceinline__ float bf2f(u16 u) {
    u32 x = ((u32)u) << 16;
    float f;
    __builtin_memcpy(&f, &x, 4);
    return f;
}
// round-to-nearest-even float -> bf16 (finite inputs)
__device__ __forceinline__ u16 f2bf(float f) {
    u32 x;
    __builtin_memcpy(&x, &f, 4);
    u32 r = x + 0x7fffu + ((x >> 16) & 1u);
    return (u16)(r >> 16);
}

// ======================= fused count (E+V single pass) + cvt =======================
extern __shared__ u32 dyn_lds[];

__global__ __launch_bounds__(1024) void count_cvt(const int* __restrict__ e_idx,
                                                  const int* __restrict__ v_idx,
                                                  u32* __restrict__ counts_e32,
                                                  u32* __restrict__ counts_v32,
                                                  int nnz, int m, int n,
                                                  const float4* __restrict__ X,  ushort4* __restrict__ Xb,  int nX,
                                                  const float4* __restrict__ W1, ushort4* __restrict__ W1b, int nW1,
                                                  const float4* __restrict__ W2, ushort4* __restrict__ W2b, int nW2)
{
    int t = threadIdx.x;
    if ((int)blockIdx.x < NB) {
        int ew = (m + 3) >> 2;
        int vw = (n + 3) >> 2;
        u32* he = dyn_lds;
        u32* hv = dyn_lds + ew;
        int tot = ew + vw;
        for (int w = t; w < tot; w += CT) dyn_lds[w] = 0;
        __syncthreads();
        int r = blockIdx.x;
        int chunk = (nnz + NB - 1) / NB;
        int beg = r * chunk, end = min(nnz, beg + chunk);
        for (int i = beg + t; i < end; i += CT) {
            int e = e_idx[i];
            int v = v_idx[i];
            atomicAdd(&he[e >> 2], 1u << ((e & 3) * 8));
            atomicAdd(&hv[v >> 2], 1u << ((v & 3) * 8));
        }
        __syncthreads();
        u32* rowe = counts_e32 + (size_t)r * ew;
        for (int w = t; w < ew; w += CT) rowe[w] = he[w];
        u32* rowv = counts_v32 + (size_t)r * vw;
        for (int w = t; w < vw; w += CT) rowv[w] = hv[w];
    } else {
        int b = blockIdx.x - NB;
        int ntot = nX + nW1 + nW2;
        for (int i = b * CT + t; i < ntot; i += NCVT * CT) {
            const float4* s; ushort4* d; int k;
            if (i < nX)            { s = X;  d = Xb;  k = i; }
            else if (i < nX + nW1) { s = W1; d = W1b; k = i - nX; }
            else                   { s = W2; d = W2b; k = i - nX - nW1; }
            float4 v = s[k];
            ushort4 o;
            o.x = f2bf(v.x); o.y = f2bf(v.y); o.z = f2bf(v.z); o.w = f2bf(v.w);
            d[k] = o;
        }
    }
}

// Word-packed (u8x4) pipelined column scan over NB rows.
__global__ __launch_bounds__(SCAN_T) void scan_block_both(u32* __restrict__ counts_e32,
                                                          u32* __restrict__ counts_v32,
                                                          int* __restrict__ e_off,
                                                          int* __restrict__ v_off,
                                                          int* __restrict__ bsums,
                                                          int m, int n, int nbE)
{
    __shared__ int s[SCAN_T];
    u32* mat; int* out; int* bs; int nwords; int blk; int nn;
    if ((int)blockIdx.x < nbE) { mat = counts_e32; out = e_off; bs = bsums;      nwords = (m + 3) >> 2; blk = blockIdx.x;       nn = m; }
    else                       { mat = counts_v32; out = v_off; bs = bsums + 64; nwords = (n + 3) >> 2; blk = blockIdx.x - nbE; nn = n; }
    int w = blk * SCAN_T + threadIdx.x;
    u32 a = 0;                                   // packed u8x4 running bases
    if (w < nwords) {
        for (int r = 0; r < NB; r += 8) {
            u32 v[8];
#pragma unroll
            for (int k = 0; k < 8; ++k) v[k] = mat[(size_t)(r + k) * nwords + w];
#pragma unroll
            for (int k = 0; k < 8; ++k) {
                mat[(size_t)(r + k) * nwords + w] = a;
                a += v[k];                       // bytewise (no carry by construction)
            }
        }
    }
    int b0 = a & 0xff, b1 = (a >> 8) & 0xff, b2 = (a >> 16) & 0xff, b3 = (int)(a >> 24);
    int x = b0 + b1 + b2 + b3;
    s[threadIdx.x] = x;
    __syncthreads();
    for (int off = 1; off < SCAN_T; off <<= 1) {
        int v = (threadIdx.x >= off) ? s[threadIdx.x - off] : 0;
        __syncthreads();
        s[threadIdx.x] += v;
        __syncthreads();
    }
    if (w < nwords) {
        int ex = s[threadIdx.x] - x;             // exclusive over buckets (block-local)
        int base = 4 * w;
        if (base + 3 < nn) {
            int4 o; o.x = ex; o.y = ex + b0; o.z = ex + b0 + b1; o.w = ex + b0 + b1 + b2;
            *(int4*)&out[base] = o;
        } else {
            if (base     < nn) out[base]     = ex;
            if (base + 1 < nn) out[base + 1] = ex + b0;
            if (base + 2 < nn) out[base + 2] = ex + b0 + b1;
            if (base + 3 < nn) out[base + 3] = ex + b0 + b1 + b2;
        }
    }
    if (threadIdx.x == SCAN_T - 1) bs[blk] = s[SCAN_T - 1];
}

// scan_top merged into scan_add: each block recomputes its bsums prefix in-block.
__global__ __launch_bounds__(SCAN_T) void scan_addtop(int* __restrict__ e_off,
                                                      int* __restrict__ v_off,
                                                      const int* __restrict__ bsums,
                                                      int m, int n, int nbE, int nnz)
{
    __shared__ int s[SCAN_T];
    int* out; const int* bs; int nwords; int blk; int nn;
    if ((int)blockIdx.x < nbE) { out = e_off; bs = bsums;      nwords = (m + 3) >> 2; blk = blockIdx.x;       nn = m; }
    else                       { out = v_off; bs = bsums + 64; nwords = (n + 3) >> 2; blk = blockIdx.x - nbE; nn = n; }
    int t = threadIdx.x;
    s[t] = (t < blk) ? bs[t] : 0;
    __syncthreads();
    for (int off = 1; off < SCAN_T; off <<= 1) {
        int v = (t >= off) ? s[t - off] : 0;
        __syncthreads();
        s[t] += v;
        __syncthreads();
    }
    int add = s[SCAN_T - 1];
    if ((int)blockIdx.x == 0   && t == 0) e_off[m] = nnz;
    if ((int)blockIdx.x == nbE && t == 0) v_off[n] = nnz;
    int w = blk * SCAN_T + t;
    if (w < nwords) {
        int base = 4 * w;
        if (base + 3 < nn) {
            int4 o = *(int4*)&out[base];
            o.x += add; o.y += add; o.z += add; o.w += add;
            *(int4*)&out[base] = o;
        } else {
            if (base     < nn) out[base]     += add;
            if (base + 1 < nn) out[base + 1] += add;
            if (base + 2 < nn) out[base + 2] += add;
            if (base + 3 < nn) out[base + 3] += add;
        }
    }
}

// Single-pass scatter: both cursor sets in 120 KB dynamic LDS, zero global atomics.
__global__ __launch_bounds__(1024) void scatter_all(const int* __restrict__ e_idx,
                                                    const int* __restrict__ v_idx,
                                                    const u32* __restrict__ counts_e32,
                                                    const u32* __restrict__ counts_v32,
                                                    const int* __restrict__ e_off,
                                                    const int* __restrict__ v_off,
                                                    int* __restrict__ e_list,
                                                    int* __restrict__ v_list,
                                                    int nnz, int m, int n)
{
    int t = threadIdx.x;
    int ew = (m + 3) >> 2;
    int vw = (n + 3) >> 2;
    u32* ce = dyn_lds;
    u32* cv = dyn_lds + ew;
    int r = blockIdx.x;
    const u32* rowe = counts_e32 + (size_t)r * ew;
    for (int w = t; w < ew; w += CT) ce[w] = rowe[w];
    const u32* rowv = counts_v32 + (size_t)r * vw;
    for (int w = t; w < vw; w += CT) cv[w] = rowv[w];
    __syncthreads();
    int chunk = (nnz + NB - 1) / NB;
    int beg = r * chunk, end = min(nnz, beg + chunk);
    for (int i = beg + t; i < end; i += CT) {
        int e = e_idx[i];
        int v = v_idx[i];
        int she = (e & 3) * 8;
        u32 olde = atomicAdd(&ce[e >> 2], 1u << she);
        e_list[e_off[e] + (int)((olde >> she) & 0xffu)] = v;
        int shv = (v & 3) * 8;
        u32 oldv = atomicAdd(&cv[v >> 2], 1u << shv);
        v_list[v_off[v] + (int)((oldv >> shv) & 0xffu)] = e;
    }
}

// ======================= segment mean: wave-per-segment =======================
// D = 256: 64 lanes x ushort4 (8 B/lane). 8-deep row pipeline.
__global__ void seg_mean_w4(const ushort4* __restrict__ src, ushort4* __restrict__ dst,
                            const int* __restrict__ off, const int* __restrict__ lst,
                            int nseg, int do_relu)
{
    int wid  = (blockIdx.x * blockDim.x + threadIdx.x) >> 6;
    int lane = threadIdx.x & 63;
    if (wid >= nseg) return;
    int beg = __builtin_amdgcn_readfirstlane(off[wid]);
    int end = __builtin_amdgcn_readfirstlane(off[wid + 1]);
    float ax = 0.f, ay = 0.f, az = 0.f, aw = 0.f;
    int j = beg;
    for (; j + 7 < end; j += 8) {
        ushort4 r[8];
#pragma unroll
        for (int k = 0; k < 8; ++k) r[k] = src[(size_t)lst[j + k] * 64 + lane];
#pragma unroll
        for (int k = 0; k < 8; ++k) {
            ax += bf2f(r[k].x); ay += bf2f(r[k].y);
            az += bf2f(r[k].z); aw += bf2f(r[k].w);
        }
    }
    for (; j + 3 < end; j += 4) {
        ushort4 r[4];
#pragma unroll
        for (int k = 0; k < 4; ++k) r[k] = src[(size_t)lst[j + k] * 64 + lane];
#pragma unroll
        for (int k = 0; k < 4; ++k) {
            ax += bf2f(r[k].x); ay += bf2f(r[k].y);
            az += bf2f(r[k].z); aw += bf2f(r[k].w);
        }
    }
    for (; j < end; ++j) {
        ushort4 a = src[(size_t)lst[j] * 64 + lane];
        ax += bf2f(a.x); ay += bf2f(a.y); az += bf2f(a.z); aw += bf2f(a.w);
    }
    int cnt = end - beg;
    float inv = (cnt > 0) ? 1.f / (float)cnt : 0.f;
    ax *= inv; ay *= inv; az *= inv; aw *= inv;
    if (do_relu) {
        ax = fmaxf(ax, 0.f); ay = fmaxf(ay, 0.f);
        az = fmaxf(az, 0.f); aw = fmaxf(aw, 0.f);
    }
    ushort4 o;
    o.x = f2bf(ax); o.y = f2bf(ay); o.z = f2bf(az); o.w = f2bf(aw);
    dst[(size_t)wid * 64 + lane] = o;
}

// D = 128: ushort2 per lane (conv2 v2e on pre-GEMM'd h1W; 256 B rows, 25.6 MB src).
__global__ void seg_mean_w2(const ushort2* __restrict__ src, ushort2* __restrict__ dst,
                            const int* __restrict__ off, const int* __restrict__ lst,
                            int nseg, int do_relu)
{
    int wid  = (blockIdx.x * blockDim.x + threadIdx.x) >> 6;
    int lane = threadIdx.x & 63;
    if (wid >= nseg) return;
    int beg = __builtin_amdgcn_readfirstlane(off[wid]);
    int end = __builtin_amdgcn_readfirstlane(off[wid + 1]);
    float ax = 0.f, ay = 0.f;
    int j = beg;
    for (; j + 7 < end; j += 8) {
        ushort2 r[8];
#pragma unroll
        for (int k = 0; k < 8; ++k) r[k] = src[(size_t)lst[j + k] * 64 + lane];
#pragma unroll
        for (int k = 0; k < 8; ++k) { ax += bf2f(r[k].x); ay += bf2f(r[k].y); }
    }
    for (; j + 3 < end; j += 4) {
        ushort2 r[4];
#pragma unroll
        for (int k = 0; k < 4; ++k) r[k] = src[(size_t)lst[j + k] * 64 + lane];
#pragma unroll
        for (int k = 0; k < 4; ++k) { ax += bf2f(r[k].x); ay += bf2f(r[k].y); }
    }
    for (; j < end; ++j) {
        ushort2 a = src[(size_t)lst[j] * 64 + lane];
        ax += bf2f(a.x); ay += bf2f(a.y);
    }
    int cnt = end - beg;
    float inv = (cnt > 0) ? 1.f / (float)cnt : 0.f;
    ax *= inv; ay *= inv;
    if (do_relu) { ax = fmaxf(ax, 0.f); ay = fmaxf(ay, 0.f); }
    ushort2 o;
    o.x = f2bf(ax); o.y = f2bf(ay);
    dst[(size_t)wid * 64 + lane] = o;
}

// ======================= fused e2v mean + ReLU + fc dot (conv2 head fold) =======================
__global__ void seg_mean_link(const ushort2* __restrict__ src, float* __restrict__ z,
                              const int* __restrict__ off, const int* __restrict__ lst,
                              const float* __restrict__ fc_w, int nseg)
{
    int wid  = (blockIdx.x * blockDim.x + threadIdx.x) >> 6;
    int lane = threadIdx.x & 63;
    if (wid >= nseg) return;
    int beg = __builtin_amdgcn_readfirstlane(off[wid]);
    int end = __builtin_amdgcn_readfirstlane(off[wid + 1]);
    float ax = 0.f, ay = 0.f;
    int j = beg;
    for (; j + 7 < end; j += 8) {
        ushort2 r[8];
#pragma unroll
        for (int k = 0; k < 8; ++k) r[k] = src[(size_t)lst[j + k] * 64 + lane];
#pragma unroll
        for (int k = 0; k < 8; ++k) { ax += bf2f(r[k].x); ay += bf2f(r[k].y); }
    }
    for (; j + 3 < end; j += 4) {
        ushort2 r[4];
#pragma unroll
        for (int k = 0; k < 4; ++k) r[k] = src[(size_t)lst[j + k] * 64 + lane];
#pragma unroll
        for (int k = 0; k < 4; ++k) { ax += bf2f(r[k].x); ay += bf2f(r[k].y); }
    }
    for (; j < end; ++j) {
        ushort2 a = src[(size_t)lst[j] * 64 + lane];
        ax += bf2f(a.x); ay += bf2f(a.y);
    }
    int cnt = end - beg;
    float inv = (cnt > 0) ? 1.f / (float)cnt : 0.f;
    ax = fmaxf(ax * inv, 0.f);
    ay = fmaxf(ay * inv, 0.f);
    float2 w = *(const float2*)&fc_w[2 * lane];
    float p = ax * w.x + ay * w.y;
#pragma unroll
    for (int off2 = 32; off2; off2 >>= 1) p += __shfl_xor(p, off2, 64);
    if (lane == 0) z[wid] = p;
}

// ======================= MFMA bf16 GEMM + bias, bf16 out =======================
#define GSTRIDE 40   // LDS row stride in elements (80 B)
__global__ __launch_bounds__(256) void gemm_mfma_bf16(const u16* __restrict__ A,
                                                      const u16* __restrict__ W,
                                                      const float* __restrict__ bias,
                                                      u16* __restrict__ C,
                                                      int R, int K, int Cc)
{
    __shared__ __align__(16) u16 As[64 * GSTRIDE];   // [row][k] 64x32
    __shared__ __align__(16) u16 Bs[64 * GSTRIDE];   // [n][k]   64x32 (transposed)

    int tid  = threadIdx.x;
    int wave = tid >> 6;
    int lane = tid & 63;
    int quad = lane >> 4;
    int l16  = lane & 15;

    int row0 = blockIdx.y * 64;
    int col0 = blockIdx.x * 64;

    f32x4 acc[4] = {};

    int ar   = tid >> 2;   // 0..63 A row
    int aseg = tid & 3;    // k-offset 8*aseg
    int bk   = tid >> 3;   // 0..31 W k-row
    int bn   = tid & 7;    // n-offset 8*bn

    for (int k0 = 0; k0 < K; k0 += 32) {
        bf16x8 av = {};
        int gr = row0 + ar;
        if (gr < R) av = *(const bf16x8*)&A[(size_t)gr * K + k0 + 8 * aseg];
        *(bf16x8*)&As[ar * GSTRIDE + 8 * aseg] = av;
        bf16x8 wv = *(const bf16x8*)&W[(size_t)(k0 + bk) * Cc + col0 + 8 * bn];
#pragma unroll
        for (int j = 0; j < 8; ++j)
            Bs[(8 * bn + j) * GSTRIDE + bk] = ((const u16*)&wv)[j];
        __syncthreads();

        bf16x8 af = *(const bf16x8*)&As[(16 * wave + l16) * GSTRIDE + 8 * quad];
#pragma unroll
        for (int nt = 0; nt < 4; ++nt) {
            bf16x8 bfv = *(const bf16x8*)&Bs[(16 * nt + l16) * GSTRIDE + 8 * quad];
            acc[nt] = __builtin_amdgcn_mfma_f32_16x16x32_bf16(af, bfv, acc[nt], 0, 0, 0);
        }
        __syncthreads();
    }

#pragma unroll
    for (int nt = 0; nt < 4; ++nt) {
        int col = col0 + 16 * nt + l16;
        float bv = bias[col];
#pragma unroll
        for (int r = 0; r < 4; ++r) {
            int grow = row0 + 16 * wave + 4 * quad + r;
            if (grow < R) C[(size_t)grow * Cc + col] = f2bf(acc[nt][r] + bv);
        }
    }
}

// ======================= scalar link head (z-based) =======================
__global__ void link_head_z(const float* __restrict__ z, const int* __restrict__ link,
                            const float* __restrict__ fc_b, float* __restrict__ out, int L)
{
    int i = blockIdx.x * blockDim.x + threadIdx.x;
    if (i >= L) return;
    int a = link[2 * i + 0];
    int b = link[2 * i + 1];
    float s = 0.5f * (z[a] + z[b]) + fc_b[0];
    out[i] = 1.f / (1.f + expf(-s));
}

// ======================= launch =======================

static inline size_t align_up(size_t x, size_t a) { return (x + a - 1) & ~(a - 1); }

extern "C" void kernel_launch(void* const* d_in, const int* in_sizes, int n_in,
                              void* d_out, int out_size, void* d_ws, size_t ws_size,
                              hipStream_t stream)
{
    const float* X   = (const float*)d_in[0];
    const float* W1  = (const float*)d_in[1];
    const float* b1  = (const float*)d_in[2];
    const float* W2  = (const float*)d_in[3];
    const float* b2  = (const float*)d_in[4];
    const float* fcw = (const float*)d_in[5];
    const float* fcb = (const float*)d_in[6];
    const int* v_idx = (const int*)d_in[7];
    const int* e_idx = (const int*)d_in[8];
    const int* link  = (const int*)d_in[9];
    float* out = (float*)d_out;

    const int NNZ = in_sizes[7];
    const int N   = in_sizes[0] / IN_DIM;
    const int L   = in_sizes[9] / 2;
    const int M   = MEDGES;

    char* p = (char*)d_ws;
    auto carve = [&](size_t bytes) -> void* {
        void* r = (void*)p;
        p += align_up(bytes, 256);
        return r;
    };
    u16*  Xb    = (u16*)carve((size_t)N * IN_DIM * 2);   // X bf16; reused as h1W (N x 128) after conv1 v2e
    u16*  h1b   = (u16*)carve((size_t)N * H_DIM * 2);    // h1 bf16
    u16*  Aggb  = (u16*)carve((size_t)M * H_DIM * 2);    // Xe bf16 (conv1 GEMM A)
    u16*  Yb    = (u16*)carve((size_t)M * H_DIM * 2);    // Y1b / Y2b
    u16*  W1b   = (u16*)carve((size_t)IN_DIM * H_DIM * 2);
    u16*  W2b   = (u16*)carve((size_t)H_DIM * OUT_DIM * 2);
    int*  e_off = (int*)carve((size_t)(M + 1) * 4);
    int*  v_off = (int*)carve((size_t)(N + 1) * 4);
    int*  e_lst = (int*)carve((size_t)NNZ * 4);
    int*  v_lst = (int*)carve((size_t)NNZ * 4);
    int*  bsums = (int*)carve(2048);                     // [0,64) E, [64,64+nbV) V
    float* zv   = (float*)carve((size_t)N * 4);          // per-vertex head scalar

    // u8x4 counts matrices aliased onto h1b (51.2 MB). Lifetime = count_cvt ..
    // scatter_all, all strictly BEFORE the first h1b write (conv1 e2v seg_mean).
    int EW = (M + 3) >> 2;
    int VW = (N + 3) >> 2;
    u32* counts_e32 = (u32*)h1b;
    u32* counts_v32 = counts_e32 + (size_t)NB * EW;

    const int tb = 256;
    const int DYN = (EW + VW) * 4;                       // 120 KB dynamic LDS

    // opt-in for >64 KB dynamic LDS (host-side, graph-capture safe; idempotent)
    (void)hipFuncSetAttribute((const void*)count_cvt,  hipFuncAttributeMaxDynamicSharedMemorySize, DYN);
    (void)hipFuncSetAttribute((const void*)scatter_all, hipFuncAttributeMaxDynamicSharedMemorySize, DYN);

    // fused single-pass E+V count + fp32->bf16 converts (cvt fills idle CUs)
    int nX  = N * IN_DIM / 4;
    int nW1 = IN_DIM * H_DIM / 4;
    int nW2 = H_DIM * OUT_DIM / 4;
    count_cvt<<<NB + NCVT, CT, DYN, stream>>>(e_idx, v_idx, counts_e32, counts_v32,
                                              NNZ, M, N,
                                              (const float4*)X, (ushort4*)Xb, nX,
                                              (const float4*)W1, (ushort4*)W1b, nW1,
                                              (const float4*)W2, (ushort4*)W2b, nW2);

    // u8x4 word-packed pipelined column scan: thread owns 4 buckets (1 u32 word)
    int nbE = (EW + SCAN_T - 1) / SCAN_T;    // 20
    int nbV = (VW + SCAN_T - 1) / SCAN_T;    // 98
    scan_block_both<<<nbE + nbV, SCAN_T, 0, stream>>>(counts_e32, counts_v32,
                                                      e_off, v_off, bsums, M, N, nbE);
    scan_addtop<<<nbE + nbV, SCAN_T, 0, stream>>>(e_off, v_off, bsums, M, N, nbE, NNZ);

    // single-pass scatter (both sides per element), zero global atomics
    scatter_all<<<NB, CT, DYN, stream>>>(e_idx, v_idx, counts_e32, counts_v32,
                                         e_off, v_off, e_lst, v_lst, NNZ, M, N);

    // ---- conv1 ----
    seg_mean_w4<<<((size_t)M * 64 + tb - 1) / tb, tb, 0, stream>>>(
        (const ushort4*)Xb, (ushort4*)Aggb, e_off, e_lst, M, 0);
    gemm_mfma_bf16<<<dim3(H_DIM / 64, (M + 63) / 64), 256, 0, stream>>>(Aggb, W1b, b1, Yb, M, IN_DIM, H_DIM);
    seg_mean_w4<<<((size_t)N * 64 + tb - 1) / tb, tb, 0, stream>>>(
        (const ushort4*)Yb, (ushort4*)h1b, v_off, v_lst, N, 1);

    // ---- conv2 (GEMM-before-gather: linearity of mean) ----
    // h1W = h1@W2 + b2 over ALL N vertices (100K x 128, 25.6 MB, aliased into Xb
    // which is dead after conv1's v2e gather). The v2e gather then reads 256 B
    // rows from a 25.6 MB source instead of 512 B rows from 51.2 MB — requested
    // bytes halve, and the order matches the reference (Xt = h1@W2 before means).
    u16* h1W = Xb;
    gemm_mfma_bf16<<<dim3(OUT_DIM / 64, (N + 63) / 64), 256, 0, stream>>>(h1b, W2b, b2, h1W, N, H_DIM, OUT_DIM);
    seg_mean_w2<<<((size_t)M * 64 + tb - 1) / tb, tb, 0, stream>>>(
        (const ushort2*)h1W, (ushort2*)Yb, e_off, e_lst, M, 0);
    // fused e2v mean + relu + fc dot -> z (h2 never materialized)
    seg_mean_link<<<((size_t)N * 64 + tb - 1) / tb, tb, 0, stream>>>(
        (const ushort2*)Yb, zv, v_off, v_lst, fcw, N);

    // ---- link head (scalar) ----
    link_head_z<<<(L + tb - 1) / tb, tb, 0, stream>>>(zv, link, fcb, out, L);
}